// Round 6
// baseline (299.384 us; speedup 1.0000x reference)
//
#include <hip/hip_runtime.h>
#include <hip/hip_bf16.h>
#include <math.h>

#define N_  128
#define D_  512
#define L_  512
#define K_  512
#define KH_ 256       // mirror symmetry: out[..,k] == out[..,511-k]
#define M_  (N_*D_)   // 65536

typedef __bf16 bf16x8 __attribute__((ext_vector_type(8)));
typedef float  f32x4  __attribute__((ext_vector_type(4)));
typedef unsigned short ushort_t;

// ---------------------------------------------------------------------------
// Kernel 1: bf16 DFT basis for k = 0..255 (exact mirror symmetry:
// ang(l,511-k) = 2*pi*l - ang(l,k) => cos equal, sin negated, |X| equal).
// Row-major [n][l]. Window tables: P=a*e, Q=-(1-a)*e, e=exp(sigma/511),
// C[l]=cos(2*pi*l/511).
// ---------------------------------------------------------------------------
__global__ void basis_kernel(const float* __restrict__ a,
                             const float* __restrict__ sigma,
                             ushort_t* __restrict__ Bc,
                             ushort_t* __restrict__ Bs,
                             float* __restrict__ P,
                             float* __restrict__ Q,
                             float* __restrict__ C) {
    int idx = blockIdx.x * 256 + threadIdx.x;   // 0 .. 256*512-1
    int r = idx >> 9;    // n (0..255)
    int c = idx & 511;   // l
    unsigned m = (unsigned)(r * c) % 511u;      // exact periodic reduction
    const float w0 = 6.283185307179586f / 511.0f;
    float sn, cs;
    sincosf((float)m * w0, &sn, &cs);
    __hip_bfloat16 bc = __float2bfloat16(cs);
    __hip_bfloat16 bs = __float2bfloat16(sn);
    ushort_t uc, us;
    __builtin_memcpy(&uc, &bc, 2);
    __builtin_memcpy(&us, &bs, 2);
    Bc[idx] = uc;
    Bs[idx] = us;
    if (idx < 512) {
        float e = expf(sigma[idx] * (1.0f / 511.0f));
        P[idx] = a[idx] * e;
        Q[idx] = -(1.0f - a[idx]) * e;
        C[idx] = cosf((float)idx * w0);
    }
}

static __device__ __forceinline__ unsigned pack_bf16x2(float lo, float hi) {
    __hip_bfloat162 h = __float22bfloat162_rn(make_float2(lo, hi));
    unsigned u;
    __builtin_memcpy(&u, &h, 4);
    return u;   // lo in low 16 bits -> memory order [lo, hi]
}

static __device__ __forceinline__ void load_lds_128(const void* g, void* l) {
    __builtin_amdgcn_global_load_lds(
        (const __attribute__((address_space(1))) unsigned int*)g,
        (__attribute__((address_space(3))) unsigned int*)l,
        16, 0, 0);
}

// ---------------------------------------------------------------------------
// Kernel 2: fused GEMM, occupancy-first redesign (3 waves/SIMD target).
//  - BM=64, BN=128-dual, BK=32; 4 waves, each 64x32-dual -> acc = 64 regs.
//  - A: fp32 x staged via global_load_lds (pre-swizzled source, linear dest,
//    XOR-by-(row&7) on 16B chunks). Window (P+Q*C) + bf16 pack applied at
//    FRAG-READ time: no xv registers, no ds_writes, minimal arch VGPRs.
//    Frag-read conflict check: 8 lanes/16B-chunk = 2 lanes/bank = free.
//  - B: r1-verified global_load_lds + XOR swizzle, byte-identical math.
//  - 2-phase double-buffer, one barrier/iter; 48 KB LDS -> 3 blocks/CU.
//  - XCD-chunked swizzle (2048 = 8*256): n-siblings of an x-panel adjacent
//    on the same XCD -> second read of the panel is an L2 hit.
// ---------------------------------------------------------------------------
__global__ __launch_bounds__(256, 3)
void dft_gemm8(const float* __restrict__ x,
               const ushort_t* __restrict__ Bc,
               const ushort_t* __restrict__ Bs,
               const float* __restrict__ P,
               const float* __restrict__ Q,
               const float* __restrict__ C,
               float* __restrict__ out) {
    __shared__ float    sA [2 * 64 * 32];    // fp32 A tiles: 2 x 8 KB
    __shared__ ushort_t sBc[2 * 128 * 32];   // 2 x 8 KB
    __shared__ ushort_t sBs[2 * 128 * 32];   // 2 x 8 KB

    const int b  = blockIdx.x;               // 2048 blocks
    const int wg = (b & 7) * 256 + (b >> 3); // XCD-chunked bijection
    const int ng = wg & 1;
    const int mg = wg >> 1;
    const int m0 = mg * 64;
    const int n0 = ng * 128;
    const int d0 = m0 & (D_ - 1);            // 64-row panel never crosses D

    const int tid  = threadIdx.x;
    const int w    = tid >> 6;
    const int lane = tid & 63;
    const int ml   = lane & 15;
    const int quad = lane >> 4;

    // ---- A staging sources: 64 rows x 8 fp32-16B-chunks, 2 issues/thread --
    // phys chunk pc holds logical chunk lc = pc ^ (row&7); row+32 same XOR.
    const int arA = tid >> 3;                // 0..31
    const int pcA = tid & 7;
    const int lcA = pcA ^ (arA & 7);
    const float* aS0 = x + (size_t)(m0 + arA) * L_ + lcA * 4;
    const float* aS1 = x + (size_t)(m0 + 32 + arA) * L_ + lcA * 4;

    // ---- B staging sources (r1-verified swizzle) ----
    const int brB = tid >> 2;                // 0..63
    const int bqB = (tid & 3) ^ ((brB >> 1) & 3);   // same for row+64
    const ushort_t* bcS0 = Bc + (size_t)(n0 + brB) * L_ + bqB * 8;
    const ushort_t* bcS1 = Bc + (size_t)(n0 + 64 + brB) * L_ + bqB * 8;
    const ushort_t* bsS0 = Bs + (size_t)(n0 + brB) * L_ + bqB * 8;
    const ushort_t* bsS1 = Bs + (size_t)(n0 + 64 + brB) * L_ + bqB * 8;

    // ---- fragment read offsets ----
    // A (float units): row ar, k-chunks 2q,2q+1 xored by (ar&7)
    int aOff0[4], aOff1[4];
#pragma unroll
    for (int mi = 0; mi < 4; ++mi) {
        int ar = mi * 16 + ml;
        int s  = ar & 7;
        aOff0[mi] = ar * 32 + ((2 * quad) ^ s) * 4;
        aOff1[mi] = ar * 32 + ((2 * quad + 1) ^ s) * 4;
    }
    // B (ushort units): r1-verified
    int bOff[2];
#pragma unroll
    for (int ni = 0; ni < 2; ++ni) {
        int br = w * 32 + ni * 16 + ml;
        int pc = quad ^ ((br >> 1) & 3);
        bOff[ni] = br * 32 + pc * 8;
    }

    // window row constants (one per m-frag)
    float pa[4], qa[4];
#pragma unroll
    for (int mi = 0; mi < 4; ++mi) {
        pa[mi] = P[d0 + mi * 16 + ml];
        qa[mi] = Q[d0 + mi * 16 + ml];
    }
    const float* Cq = C + quad * 8;          // per-lane window cosine base

    f32x4 acc_c[4][2], acc_s[4][2];
    const f32x4 zero = {0.f, 0.f, 0.f, 0.f};
#pragma unroll
    for (int mi = 0; mi < 4; ++mi)
#pragma unroll
        for (int ni = 0; ni < 2; ++ni) { acc_c[mi][ni] = zero; acc_s[mi][ni] = zero; }

#define STAGE(buf, kk)                                                        \
    do {                                                                      \
        const int fo_ = (buf) * 2048;   /* floats  */                         \
        const int uo_ = (buf) * 4096;   /* ushorts */                         \
        load_lds_128(aS0  + (kk), sA  + fo_ + w * 256);                       \
        load_lds_128(aS1  + (kk), sA  + fo_ + 1024 + w * 256);                \
        load_lds_128(bcS0 + (kk), sBc + uo_ + w * 512);                       \
        load_lds_128(bcS1 + (kk), sBc + uo_ + 2048 + w * 512);                \
        load_lds_128(bsS0 + (kk), sBs + uo_ + w * 512);                       \
        load_lds_128(bsS1 + (kk), sBs + uo_ + 2048 + w * 512);                \
    } while (0)

    auto compute_tile = [&](int buf, int kk) {
        const int fo = buf * 2048;
        const int uo = buf * 4096;
        // window cosine chunk for this lane's k-slots (2 KB table, L1)
        float4 cv0 = *(const float4*)(Cq + kk);
        float4 cv1 = *(const float4*)(Cq + kk + 4);
        // A frags: fp32 LDS read -> window fma -> bf16 pack (in regs)
        bf16x8 af[4];
#pragma unroll
        for (int mi = 0; mi < 4; ++mi) {
            float4 f0 = *(const float4*)&sA[fo + aOff0[mi]];
            float4 f1 = *(const float4*)&sA[fo + aOff1[mi]];
            float p = pa[mi], q = qa[mi];
            int4 pk;
            pk.x = (int)pack_bf16x2(f0.x * fmaf(q, cv0.x, p),
                                    f0.y * fmaf(q, cv0.y, p));
            pk.y = (int)pack_bf16x2(f0.z * fmaf(q, cv0.z, p),
                                    f0.w * fmaf(q, cv0.w, p));
            pk.z = (int)pack_bf16x2(f1.x * fmaf(q, cv1.x, p),
                                    f1.y * fmaf(q, cv1.y, p));
            pk.w = (int)pack_bf16x2(f1.z * fmaf(q, cv1.z, p),
                                    f1.w * fmaf(q, cv1.w, p));
            __builtin_memcpy(&af[mi], &pk, 16);
        }
        // B frags + MFMA
#pragma unroll
        for (int ni = 0; ni < 2; ++ni) {
            bf16x8 bcf = *(const bf16x8*)&sBc[uo + bOff[ni]];
            bf16x8 bsf = *(const bf16x8*)&sBs[uo + bOff[ni]];
#pragma unroll
            for (int mi = 0; mi < 4; ++mi) {
                acc_c[mi][ni] = __builtin_amdgcn_mfma_f32_16x16x32_bf16(
                    af[mi], bcf, acc_c[mi][ni], 0, 0, 0);
                acc_s[mi][ni] = __builtin_amdgcn_mfma_f32_16x16x32_bf16(
                    af[mi], bsf, acc_s[mi][ni], 0, 0, 0);
            }
        }
    };

    // ---- 2-phase pipeline over 16 k-tiles ----
    STAGE(0, 0);
    __syncthreads();

    int cur = 0;
    for (int kk = 32; kk < L_; kk += 32) {
        STAGE(cur ^ 1, kk);          // next tile in flight during compute
        compute_tile(cur, kk - 32);
        __syncthreads();
        cur ^= 1;
    }
    compute_tile(cur, L_ - 32);

#undef STAGE

    // ---- epilogue: magnitude + exact mirror write ----
#pragma unroll
    for (int mi = 0; mi < 4; ++mi)
#pragma unroll
        for (int ni = 0; ni < 2; ++ni) {
#pragma unroll
            for (int r = 0; r < 4; ++r) {
                float cv = acc_c[mi][ni][r];
                float sv = acc_s[mi][ni][r];
                int row = m0 + mi * 16 + quad * 4 + r;
                int col = n0 + w * 32 + ni * 16 + ml;
                float v = sqrtf(cv * cv + sv * sv);
                out[(size_t)row * K_ + col] = v;
                out[(size_t)row * K_ + (K_ - 1 - col)] = v;
            }
        }
}

extern "C" void kernel_launch(void* const* d_in, const int* in_sizes, int n_in,
                              void* d_out, int out_size, void* d_ws, size_t ws_size,
                              hipStream_t stream) {
    (void)in_sizes; (void)n_in; (void)out_size; (void)ws_size;
    const float* x     = (const float*)d_in[0];
    const float* a     = (const float*)d_in[1];
    const float* sigma = (const float*)d_in[2];
    float* out = (float*)d_out;

    // ws: Bc (256KB) | Bs (256KB) | P (2KB) | Q (2KB) | C (2KB)
    ushort_t* Bc = (ushort_t*)d_ws;
    ushort_t* Bs = Bc + KH_ * 512;
    float*    P  = (float*)(Bs + KH_ * 512);
    float*    Q  = P + 512;
    float*    C  = Q + 512;

    basis_kernel<<<dim3(512), dim3(256), 0, stream>>>(a, sigma, Bc, Bs, P, Q, C);
    dft_gemm8<<<dim3(2048), dim3(256), 0, stream>>>(x, Bc, Bs, P, Q, C, out);
}

// Round 7
// 294.005 us; speedup vs baseline: 1.0183x; 1.0183x over previous
//
#include <hip/hip_runtime.h>
#include <hip/hip_bf16.h>
#include <math.h>

#define N_  128
#define D_  512
#define L_  512
#define K_  512
#define KH_ 256       // mirror symmetry: out[..,k] == out[..,511-k]
#define M_  (N_*D_)   // 65536

typedef __bf16 bf16x8 __attribute__((ext_vector_type(8)));
typedef float  f32x4  __attribute__((ext_vector_type(4)));
typedef unsigned short ushort_t;

// ---------------------------------------------------------------------------
// Kernel 1: INTERLEAVED bf16 DFT basis, rows 0..511: row 2k = cos_k,
// row 2k+1 = sin_k, k = 0..255 (exact mirror symmetry handles k=256..511:
// ang(l,511-k) = 2*pi*l - ang(l,k) => cos equal, sin negated, |X| equal).
// Layout [n_int][l] row-major. Window tables: P=a*e, Q=-(1-a)*e,
// e=exp(sigma/511), C[l]=cos(2*pi*l/511).
// ---------------------------------------------------------------------------
__global__ void basis_kernel(const float* __restrict__ a,
                             const float* __restrict__ sigma,
                             ushort_t* __restrict__ Bi,
                             float* __restrict__ P,
                             float* __restrict__ Q,
                             float* __restrict__ C) {
    int idx = blockIdx.x * 256 + threadIdx.x;   // 0 .. 512*512-1
    int r = idx >> 9;    // interleaved row (0..511)
    int c = idx & 511;   // l
    int k = r >> 1;      // spectral index 0..255
    unsigned m = (unsigned)(k * c) % 511u;      // exact periodic reduction
    const float w0 = 6.283185307179586f / 511.0f;
    float sn, cs;
    sincosf((float)m * w0, &sn, &cs);
    float val = (r & 1) ? sn : cs;
    __hip_bfloat16 bv = __float2bfloat16(val);
    ushort_t uv;
    __builtin_memcpy(&uv, &bv, 2);
    Bi[idx] = uv;
    if (idx < 512) {
        float e = expf(sigma[idx] * (1.0f / 511.0f));
        P[idx] = a[idx] * e;
        Q[idx] = -(1.0f - a[idx]) * e;
        C[idx] = cosf((float)idx * w0);
    }
}

static __device__ __forceinline__ unsigned pack_bf16x2(float lo, float hi) {
    __hip_bfloat162 h = __float22bfloat162_rn(make_float2(lo, hi));
    unsigned u;
    __builtin_memcpy(&u, &h, 4);
    return u;   // lo in low 16 bits -> memory order [lo, hi]
}

static __device__ __forceinline__ void load_lds_128(const void* g, void* l) {
    __builtin_amdgcn_global_load_lds(
        (const __attribute__((address_space(1))) unsigned int*)g,
        (__attribute__((address_space(3))) unsigned int*)l,
        16, 0, 0);
}

// ---------------------------------------------------------------------------
// Kernel 2: fused single-accumulator GEMM over the interleaved basis.
//  - BM=128, BN=128(interleaved), BK=32; 4 waves 2x2; per-wave 64x64 single
//    acc = 64 regs (dual-acc tax removed) -> __launch_bounds__(256,3) for
//    3 waves/SIMD (the m97/m114 latency-hiding regime).
//  - A: r3's verified fused reg-stage (window applied ONCE per block at
//    ds_write, T14 issue-early/write-late, XOR 16B-chunk swizzle).
//  - B: single interleaved array, global_load_lds + verified XOR swizzle.
//  - Epilogue: cos/sin pair sits in adjacent lanes (ml, ml^1):
//    sq += __shfl_xor(sq,1); even lane writes col k, odd lane writes 511-k.
//  - 2-phase double-buffer (proven schedule, unchanged); XCD-chunked
//    bijection (2048 = 8*256) keeps the 4 n-siblings of an x-panel on one
//    XCD -> x re-reads are L2 hits.
// ---------------------------------------------------------------------------
__global__ __launch_bounds__(256, 3)
void dft_gemm9(const float* __restrict__ x,
               const ushort_t* __restrict__ Bi,
               const float* __restrict__ P,
               const float* __restrict__ Q,
               const float* __restrict__ C,
               float* __restrict__ out) {
    __shared__ ushort_t sA [2 * 128 * 32];   // 2 x 8 KB
    __shared__ ushort_t sBi[2 * 128 * 32];   // 2 x 8 KB

    const int b  = blockIdx.x;               // 2048 blocks
    const int wg = (b & 7) * 256 + (b >> 3); // XCD-chunked bijection
    const int ng = wg & 3;
    const int mg = wg >> 2;
    const int m0 = mg * 128;
    const int n0 = ng * 128;                 // interleaved column base

    const int tid  = threadIdx.x;
    const int w    = tid >> 6;
    const int lane = tid & 63;
    const int ml   = lane & 15;
    const int quad = lane >> 4;

    // ---- A fused staging mapping (r3-verified): rows r0, r0+64 ----
    const int ar0 = tid >> 2;                 // 0..63
    const int ac  = tid & 3;                  // logical 8-elem k-chunk
    const int ar1 = ar0 + 64;
    const int apc = ac ^ ((ar0 >> 1) & 3);    // phys chunk (same for ar1)
    const int d0  = m0 & (D_ - 1);

    const float p0 = P[d0 + ar0], q0 = Q[d0 + ar0];
    const float p1 = P[d0 + ar1], q1 = Q[d0 + ar1];

    const float* xr0 = x + (size_t)(m0 + ar0) * L_ + ac * 8;
    const float* xr1 = x + (size_t)(m0 + ar1) * L_ + ac * 8;
    const float* Cc  = C + ac * 8;

    ushort_t* aD0 = sA + ar0 * 32 + apc * 8;  // + buf*4096
    ushort_t* aD1 = sA + ar1 * 32 + apc * 8;

    // ---- B staging via global_load_lds (verified swizzle), single array --
    const int brB = tid >> 2;                 // 0..63
    const int bqB = (tid & 3) ^ ((brB >> 1) & 3);   // same XOR for row+64
    const ushort_t* biS0 = Bi + (size_t)(n0 + brB) * L_ + bqB * 8;
    const ushort_t* biS1 = Bi + (size_t)(n0 + 64 + brB) * L_ + bqB * 8;

    const int wm = w >> 1, wn = w & 1;

    int aOff[4], bOff[4];
#pragma unroll
    for (int mi = 0; mi < 4; ++mi) {
        int ar = wm * 64 + mi * 16 + ml;
        int pc = quad ^ ((ar >> 1) & 3);
        aOff[mi] = ar * 32 + pc * 8;
    }
#pragma unroll
    for (int ni = 0; ni < 4; ++ni) {
        int br = wn * 64 + ni * 16 + ml;
        int pc = quad ^ ((br >> 1) & 3);
        bOff[ni] = br * 32 + pc * 8;
    }

    f32x4 acc[4][4];
    const f32x4 zero = {0.f, 0.f, 0.f, 0.f};
#pragma unroll
    for (int mi = 0; mi < 4; ++mi)
#pragma unroll
        for (int ni = 0; ni < 4; ++ni) acc[mi][ni] = zero;

#define STAGE_B(buf, kk)                                                      \
    do {                                                                      \
        const int bo_ = (buf) * 4096;                                         \
        load_lds_128(biS0 + (kk), sBi + bo_ + w * 512);                       \
        load_lds_128(biS1 + (kk), sBi + bo_ + 2048 + w * 512);                \
    } while (0)

    // window + bf16-pack + swizzled ds_write of one A k-tile (2 rows/thread)
    auto writeA = [&](int buf, float4 v00, float4 v01, float4 v10, float4 v11,
                      float4 cv0, float4 cv1) {
        int bo = buf * 4096;
        float w0a = fmaf(q0, cv0.x, p0), w0b = fmaf(q0, cv0.y, p0);
        float w0c = fmaf(q0, cv0.z, p0), w0d = fmaf(q0, cv0.w, p0);
        float w0e = fmaf(q0, cv1.x, p0), w0f = fmaf(q0, cv1.y, p0);
        float w0g = fmaf(q0, cv1.z, p0), w0h = fmaf(q0, cv1.w, p0);
        int4 s0;
        s0.x = (int)pack_bf16x2(v00.x * w0a, v00.y * w0b);
        s0.y = (int)pack_bf16x2(v00.z * w0c, v00.w * w0d);
        s0.z = (int)pack_bf16x2(v01.x * w0e, v01.y * w0f);
        s0.w = (int)pack_bf16x2(v01.z * w0g, v01.w * w0h);
        *(int4*)(aD0 + bo) = s0;
        float w1a = fmaf(q1, cv0.x, p1), w1b = fmaf(q1, cv0.y, p1);
        float w1c = fmaf(q1, cv0.z, p1), w1d = fmaf(q1, cv0.w, p1);
        float w1e = fmaf(q1, cv1.x, p1), w1f = fmaf(q1, cv1.y, p1);
        float w1g = fmaf(q1, cv1.z, p1), w1h = fmaf(q1, cv1.w, p1);
        int4 s1;
        s1.x = (int)pack_bf16x2(v10.x * w1a, v10.y * w1b);
        s1.y = (int)pack_bf16x2(v10.z * w1c, v10.w * w1d);
        s1.z = (int)pack_bf16x2(v11.x * w1e, v11.y * w1f);
        s1.w = (int)pack_bf16x2(v11.z * w1g, v11.w * w1h);
        *(int4*)(aD1 + bo) = s1;
    };

    auto compute_tile = [&](int buf) {
        const int bo = buf * 4096;
        bf16x8 af[4], bf[4];
#pragma unroll
        for (int mi = 0; mi < 4; ++mi)
            af[mi] = *(const bf16x8*)&sA[bo + aOff[mi]];
#pragma unroll
        for (int ni = 0; ni < 4; ++ni)
            bf[ni] = *(const bf16x8*)&sBi[bo + bOff[ni]];
#pragma unroll
        for (int mi = 0; mi < 4; ++mi)
#pragma unroll
            for (int ni = 0; ni < 4; ++ni)
                acc[mi][ni] = __builtin_amdgcn_mfma_f32_16x16x32_bf16(
                    af[mi], bf[ni], acc[mi][ni], 0, 0, 0);
    };

    // ---- prologue: tile 0 -> buf 0 ----
    float4 a00 = *(const float4*)(xr0 + 0);
    float4 a01 = *(const float4*)(xr0 + 4);
    float4 a10 = *(const float4*)(xr1 + 0);
    float4 a11 = *(const float4*)(xr1 + 4);
    float4 cv0 = *(const float4*)(Cc + 0);
    float4 cv1 = *(const float4*)(Cc + 4);
    STAGE_B(0, 0);
    writeA(0, a00, a01, a10, a11, cv0, cv1);
    __syncthreads();

    int cur = 0;
    for (int kk = 32; kk < L_; kk += 32) {
        // issue next-tile A loads FIRST (latency hides under MFMA phase)
        a00 = *(const float4*)(xr0 + kk);
        a01 = *(const float4*)(xr0 + kk + 4);
        a10 = *(const float4*)(xr1 + kk);
        a11 = *(const float4*)(xr1 + kk + 4);
        cv0 = *(const float4*)(Cc + kk);
        cv1 = *(const float4*)(Cc + kk + 4);
        STAGE_B(cur ^ 1, kk);       // B loads for next tile (async)
        compute_tile(cur);          // 8 ds_read + 16 MFMA
        writeA(cur ^ 1, a00, a01, a10, a11, cv0, cv1);  // write-late (T14)
        __syncthreads();
        cur ^= 1;
    }
    compute_tile(cur);              // last k-tile

#undef STAGE_B

    // ---- epilogue: pairwise magnitude via lane-xor, mirror write ----
    // C/D layout: col = lane&15, row = quad*4 + reg (m89/m91-verified).
    // icol even = cos branch, odd = sin branch of k = icol>>1; lanes ml and
    // ml^1 hold the pair -> shfl_xor(1) completes |X|; even lane writes k,
    // odd lane writes 511-k (exact mirror).
#pragma unroll
    for (int mi = 0; mi < 4; ++mi)
#pragma unroll
        for (int ni = 0; ni < 4; ++ni) {
#pragma unroll
            for (int r = 0; r < 4; ++r) {
                float v  = acc[mi][ni][r];
                float sq = v * v;
                sq += __shfl_xor(sq, 1);
                float mag = sqrtf(sq);
                int row  = m0 + wm * 64 + mi * 16 + quad * 4 + r;
                int icol = n0 + wn * 64 + ni * 16 + ml;
                int k    = icol >> 1;
                int col  = (icol & 1) ? (K_ - 1 - k) : k;
                out[(size_t)row * K_ + col] = mag;
            }
        }
}

extern "C" void kernel_launch(void* const* d_in, const int* in_sizes, int n_in,
                              void* d_out, int out_size, void* d_ws, size_t ws_size,
                              hipStream_t stream) {
    (void)in_sizes; (void)n_in; (void)out_size; (void)ws_size;
    const float* x     = (const float*)d_in[0];
    const float* a     = (const float*)d_in[1];
    const float* sigma = (const float*)d_in[2];
    float* out = (float*)d_out;

    // ws: Bi (512KB interleaved) | P (2KB) | Q (2KB) | C (2KB)
    ushort_t* Bi = (ushort_t*)d_ws;
    float*    P  = (float*)(Bi + 512 * 512);
    float*    Q  = P + 512;
    float*    C  = Q + 512;

    basis_kernel<<<dim3(1024), dim3(256), 0, stream>>>(a, sigma, Bi, P, Q, C);
    dft_gemm9<<<dim3(2048), dim3(256), 0, stream>>>(x, Bi, P, Q, C, out);
}